// Round 10
// baseline (2420.648 us; speedup 1.0000x reference)
//
#include <hip/hip_runtime.h>
#include <cstddef>
#include <cstdint>

// ---------------------------------------------------------------------------
// GRU sequence model (flax GRUCell, gate_fn=silu, activation=tanh)
// T=512, B=128, F_IN=1030, H=512
// Round-10 = round-9 + overlapped sync:
//   - per-wave flags: compute wave stores h -> s_waitcnt vmcnt(0) -> flag
//     (relaxed agent), no barrier before signaling; ys stores after flag.
//   - wave 7 polls the 64 group flags for step s+1 WHILE waves 0-1 compute
//     step s. 2 barriers/step (was 3), poll latency hidden under compute.
//   - WAR safety: a block writes h(s+2) (buf parity s) only after all blocks'
//     flags >= s+1, which requires every block to have consumed h(s) into LDS.
// Everything else identical to round 9 (proven):
//   128 recurrence blocks, 4 groups x 32 rows, 16 cols/block, Wh LDS-resident,
//   agent-scope flags/stores, sc0sc1 h loads; 120 GEMM workers for next xg.
// Output: [carry (B*H) | ys (T*B*H)] fp32
// ---------------------------------------------------------------------------

#define T_STEPS 512
#define BATCH   128
#define F_IN    1030
#define KPAD    1056          // 33 * 32
#define H       512
#define G3      1536          // 3*H
#define TCHUNK  32
#define NCHUNK  (T_STEPS / TCHUNK)        // 16
#define MCHUNK  (TCHUNK * BATCH)          // 4096 rows per chunk
#define NTILE_M (MCHUNK / 128)            // 32
#define NTILE_N (G3 / 256)                // 6
#define NTILE   (NTILE_M * NTILE_N)       // 192
#define RBLK    128                       // recurrence blocks
#define NWORK   120                       // worker blocks
#define FPAGE   4096                      // u32 per launch flag page
#define BUFU32  32768                     // u32 per h buffer (B*H/2)

using f32x4  = __attribute__((ext_vector_type(4)))  float;
using bf16x8 = __attribute__((ext_vector_type(8)))  short;
using u16x8  = __attribute__((ext_vector_type(8)))  unsigned short;
using u32x4  = __attribute__((ext_vector_type(4)))  unsigned int;

__device__ __forceinline__ unsigned short f2bf(float f) {
    unsigned int u = __builtin_bit_cast(unsigned int, f);
    u = (u + 0x7FFFu + ((u >> 16) & 1u)) >> 16;   // RNE
    return (unsigned short)u;
}
__device__ __forceinline__ float bf2f(unsigned short s) {
    unsigned int u = ((unsigned int)s) << 16;
    return __builtin_bit_cast(float, u);
}
__device__ __forceinline__ unsigned int cvt2bf(float lo, float hi) {
    unsigned int r;
    asm("v_cvt_pk_bf16_f32 %0, %1, %2" : "=v"(r) : "v"(lo), "v"(hi));
    return r;
}
// coherent 16B load (bypass L1+L2 staleness); caller waits vmcnt
__device__ __forceinline__ void ld4_coh(const unsigned int* p, u32x4& d) {
    asm volatile("global_load_dwordx4 %0, %1, off sc0 sc1"
                 : "=&v"(d) : "v"(p) : "memory");
}

// ---------------------------------------------------------------------------
// Wi [F_IN][G3] fp32 -> wiT [G3][KPAD] bf16 (transposed, K zero-padded)
// ---------------------------------------------------------------------------
__global__ __launch_bounds__(256) void transpose_wi(const float* __restrict__ Wi,
                                                    unsigned short* __restrict__ wiT) {
    __shared__ float t_lds[32][33];
    const int kx = blockIdx.x, gy = blockIdx.y;
    const int tx = threadIdx.x, ty = threadIdx.y;
#pragma unroll
    for (int r = 0; r < 4; ++r) {
        int k = kx * 32 + ty + r * 8;
        int g = gy * 32 + tx;
        t_lds[ty + r * 8][tx] = (k < F_IN) ? Wi[(size_t)k * G3 + g] : 0.f;
    }
    __syncthreads();
#pragma unroll
    for (int r = 0; r < 4; ++r) {
        int g = gy * 32 + ty + r * 8;
        int k = kx * 32 + tx;
        wiT[(size_t)g * KPAD + k] = f2bf(t_lds[tx][ty + r * 8]);
    }
}

// ---------------------------------------------------------------------------
// Wh_rz [H][2H], Wh_n [H][H] fp32 -> whT [G3][H] bf16 column-major
// ---------------------------------------------------------------------------
__global__ __launch_bounds__(256) void transpose_wh(const float* __restrict__ Whrz,
                                                    const float* __restrict__ Whn,
                                                    unsigned short* __restrict__ whT) {
    __shared__ float t_lds[32][33];
    const int kx = blockIdx.x, cy = blockIdx.y;
    const int tx = threadIdx.x, ty = threadIdx.y;
#pragma unroll
    for (int r = 0; r < 4; ++r) {
        int k = kx * 32 + ty + r * 8;
        int c = cy * 32 + tx;
        float v = (c < 1024) ? Whrz[(size_t)k * 1024 + c]
                             : Whn[(size_t)k * H + (c - 1024)];
        t_lds[ty + r * 8][tx] = v;
    }
    __syncthreads();
#pragma unroll
    for (int r = 0; r < 4; ++r) {
        int c = cy * 32 + ty + r * 8;
        int k = kx * 32 + tx;
        whT[(size_t)c * H + k] = f2bf(t_lds[tx][ty + r * 8]);
    }
}

// ---------------------------------------------------------------------------
// init: hx[0] = bf16(h0); zero all launch flag pages (16 x 4096 u32)
// ---------------------------------------------------------------------------
__global__ __launch_bounds__(256) void init_ws(const float* __restrict__ h0,
                                               unsigned short* __restrict__ hx,
                                               unsigned int* __restrict__ flags) {
    int i = blockIdx.x * 256 + threadIdx.x;
    flags[i] = 0u;                       // 65536 u32 = 16 pages x 4096
    if (i < BATCH * H) hx[i] = f2bf(h0[i]);
}

// ---------------------------------------------------------------------------
// Standalone xg GEMM for chunk 0. 128x128 tile, BK=32, 256 thr.
// grid (G3/128=12, MCHUNK/128=32)
// ---------------------------------------------------------------------------
__global__ __launch_bounds__(256) void gemm_xg(const float* __restrict__ x,
                                               const unsigned short* __restrict__ wiT,
                                               const float* __restrict__ bi,
                                               unsigned short* __restrict__ xg) {
    __shared__ unsigned short a_lds[128][40];
    __shared__ unsigned short b_lds[128][40];
    const int tid = threadIdx.x;
    const int n0 = blockIdx.x * 128;
    const int m0 = blockIdx.y * 128;
    const int l = tid & 63, w = tid >> 6;
    const int wr = w >> 1, wc = w & 1;
    const int sr = tid >> 1;
    const int sk = (tid & 1) * 16;

    f32x4 acc[4][4] = {};

    for (int kt = 0; kt < 33; ++kt) {
        if (kt) __syncthreads();
        {
            const int kb = kt * 32 + sk;
            const float* srcp = x + (size_t)(m0 + sr) * F_IN + kb;
            float2 f2v[8];
#pragma unroll
            for (int i = 0; i < 8; ++i) {
                int k = kb + 2 * i;
                if (k < F_IN) f2v[i] = *(const float2*)(srcp + 2 * i);
                else          f2v[i] = make_float2(0.f, 0.f);
            }
            uint4 p0, p1;
            p0.x = cvt2bf(f2v[0].x, f2v[0].y); p0.y = cvt2bf(f2v[1].x, f2v[1].y);
            p0.z = cvt2bf(f2v[2].x, f2v[2].y); p0.w = cvt2bf(f2v[3].x, f2v[3].y);
            p1.x = cvt2bf(f2v[4].x, f2v[4].y); p1.y = cvt2bf(f2v[5].x, f2v[5].y);
            p1.z = cvt2bf(f2v[6].x, f2v[6].y); p1.w = cvt2bf(f2v[7].x, f2v[7].y);
            *(uint4*)&a_lds[sr][sk]     = p0;
            *(uint4*)&a_lds[sr][sk + 8] = p1;
            const unsigned short* bsrc = wiT + (size_t)(n0 + sr) * KPAD + kb;
            *(uint4*)&b_lds[sr][sk]     = *(const uint4*)bsrc;
            *(uint4*)&b_lds[sr][sk + 8] = *(const uint4*)(bsrc + 8);
        }
        __syncthreads();
        const int ka = (l >> 4) * 8;
        bf16x8 af[4], bfr[4];
#pragma unroll
        for (int mi = 0; mi < 4; ++mi)
            af[mi] = *(const bf16x8*)&a_lds[wr * 64 + mi * 16 + (l & 15)][ka];
#pragma unroll
        for (int nj = 0; nj < 4; ++nj)
            bfr[nj] = *(const bf16x8*)&b_lds[wc * 64 + nj * 16 + (l & 15)][ka];
#pragma unroll
        for (int mi = 0; mi < 4; ++mi)
#pragma unroll
            for (int nj = 0; nj < 4; ++nj)
                acc[mi][nj] = __builtin_amdgcn_mfma_f32_16x16x32_bf16(
                    af[mi], bfr[nj], acc[mi][nj], 0, 0, 0);
    }

#pragma unroll
    for (int nj = 0; nj < 4; ++nj) {
        const int col = n0 + wc * 64 + nj * 16 + (l & 15);
        const float bv = bi[col];
#pragma unroll
        for (int mi = 0; mi < 4; ++mi) {
#pragma unroll
            for (int q = 0; q < 4; ++q) {
                const int row = m0 + wr * 64 + mi * 16 + (l >> 4) * 4 + q;
                xg[(size_t)row * G3 + col] = f2bf(acc[mi][nj][q] + bv);
            }
        }
    }
}

// ---------------------------------------------------------------------------
// Fused chunk kernel: 248 blocks x 512 thr, 83200B LDS => 1 block/CU.
// blockIdx < 128: recurrence. blockIdx >= 128: GEMM workers.
// ---------------------------------------------------------------------------
__global__ __launch_bounds__(512) void fused_chunk(
    const float* __restrict__ x_next,          // x rows for chunk c+1
    const unsigned short* __restrict__ wiT,
    const float* __restrict__ bi,
    unsigned short* __restrict__ xg_next,      // xg buffer for chunk c+1
    const unsigned short* __restrict__ xg_cur, // xg buffer for chunk c
    const unsigned short* __restrict__ whT,    // [G3][H] bf16
    const float* __restrict__ bhn,
    const float* __restrict__ hinit,           // fp32 h at t0 (h0 or ys[t0-1])
    unsigned short* __restrict__ hx,           // [2][B][H] bf16
    float* __restrict__ ys,                    // [T][B][H] fp32
    float* __restrict__ carry,                 // [B][H] fp32
    unsigned int* __restrict__ fpage,          // this launch's flag page
    int t0, int do_gemm)
{
    __shared__ __align__(16) unsigned char smem[83200];
    const int tid = threadIdx.x;
    const int bid = blockIdx.x;
    const int l = tid & 63, w = tid >> 6;

    if (bid >= RBLK) {
        // ================= GEMM worker path =================
        if (!do_gemm) return;
        unsigned short (*a_lds)[40] = (unsigned short(*)[40])smem;            // 128x40
        unsigned short (*b_lds)[40] = (unsigned short(*)[40])(smem + 10240);  // 256x40
        const int wr = w & 1, wc = w >> 1;       // 2(m) x 4(n) waves, 64x64 each
        const int sa_r = tid >> 2;               // 0..127
        const int sa_k = (tid & 3) * 8;
        const int sb_r = tid >> 1;               // 0..255
        const int sb_k = (tid & 1) * 16;

        for (int tile = bid - RBLK; tile < NTILE; tile += NWORK) {
            const int m0 = (tile & (NTILE_M - 1)) * 128;
            const int n0 = (tile / NTILE_M) * 256;
            f32x4 acc[4][4] = {};
            for (int kt = 0; kt < 33; ++kt) {
                __syncthreads();
                {
                    const int kb = kt * 32 + sa_k;
                    const float* srcp = x_next + (size_t)(m0 + sa_r) * F_IN + kb;
                    float2 f2v[4];
#pragma unroll
                    for (int i = 0; i < 4; ++i) {
                        int k = kb + 2 * i;
                        if (k < F_IN) f2v[i] = *(const float2*)(srcp + 2 * i);
                        else          f2v[i] = make_float2(0.f, 0.f);
                    }
                    uint4 p;
                    p.x = cvt2bf(f2v[0].x, f2v[0].y); p.y = cvt2bf(f2v[1].x, f2v[1].y);
                    p.z = cvt2bf(f2v[2].x, f2v[2].y); p.w = cvt2bf(f2v[3].x, f2v[3].y);
                    *(uint4*)&a_lds[sa_r][sa_k] = p;
                    const int kbB = kt * 32 + sb_k;
                    const unsigned short* bsrc = wiT + (size_t)(n0 + sb_r) * KPAD + kbB;
                    *(uint4*)&b_lds[sb_r][sb_k]     = *(const uint4*)bsrc;
                    *(uint4*)&b_lds[sb_r][sb_k + 8] = *(const uint4*)(bsrc + 8);
                }
                __syncthreads();
                const int ka = (l >> 4) * 8;
                bf16x8 af[4], bfr[4];
#pragma unroll
                for (int mi = 0; mi < 4; ++mi)
                    af[mi] = *(const bf16x8*)&a_lds[wr * 64 + mi * 16 + (l & 15)][ka];
#pragma unroll
                for (int nj = 0; nj < 4; ++nj)
                    bfr[nj] = *(const bf16x8*)&b_lds[wc * 64 + nj * 16 + (l & 15)][ka];
#pragma unroll
                for (int mi = 0; mi < 4; ++mi)
#pragma unroll
                    for (int nj = 0; nj < 4; ++nj)
                        acc[mi][nj] = __builtin_amdgcn_mfma_f32_16x16x32_bf16(
                            af[mi], bfr[nj], acc[mi][nj], 0, 0, 0);
            }
#pragma unroll
            for (int nj = 0; nj < 4; ++nj) {
                const int col = n0 + wc * 64 + nj * 16 + (l & 15);
                const float bv = bi[col];
#pragma unroll
                for (int mi = 0; mi < 4; ++mi) {
#pragma unroll
                    for (int q = 0; q < 4; ++q) {
                        const int row = m0 + wr * 64 + mi * 16 + (l >> 4) * 4 + q;
                        xg_next[(size_t)row * G3 + col] = f2bf(acc[mi][nj][q] + bv);
                    }
                }
            }
            __syncthreads();
        }
        return;
    }

    // ================= Recurrence path (bid 0..127) =================
    unsigned short (*wlds)[16][520] = (unsigned short(*)[16][520])smem;       // [3][16][520] 49920B
    unsigned short (*h_lds)[520]    = (unsigned short(*)[520])(smem + 49920); // [32][520]    33280B
    unsigned int* hl32 = (unsigned int*)(smem + 49920);                       // pitch 260 u32

    const int grp = bid >> 5;                    // 0..3 -> 32 batch rows
    const int rnk = bid & 31;                    // 0..31 -> 16 cols
    const int b0 = grp * 32;
    const int j0 = rnk * 16;
    unsigned int* flbase = fpage + grp * 1024;   // 64 flags, 64B apart
    unsigned int* flown  = flbase + (rnk * 2 + w) * 16;  // per compute wave
    const unsigned int* hx32 = (const unsigned int*)hx;
    unsigned int* hx32w = (unsigned int*)hx;

    // ---- prologue: Wh slice -> LDS (once per launch) ----
#pragma unroll
    for (int it = 0; it < 6; ++it) {
        int L = tid + it * 512;                  // 0..3071 vec8 loads
        int gate = L >> 10;                      // 1024 per gate
        int rem = L & 1023;
        int jj = rem >> 6;                       // 0..15
        int k8 = (rem & 63) * 8;                 // 0..504
        *(u16x8*)&wlds[gate][jj][k8] =
            *(const u16x8*)(whT + ((size_t)(gate * H + j0 + jj)) * H + k8);
    }

    const int col = j0 + (l & 15);
    float hreg[4];
    if (w < 2) {
#pragma unroll
        for (int q = 0; q < 4; ++q) {
            const int row = w * 16 + (l >> 4) * 4 + q;
            hreg[q] = hinit[(size_t)(b0 + row) * H + col];
        }
    }
    const float bnv = bhn[col];
    const int hrow = tid >> 4;                   // 0..31 (h staging row)
    const int hseg = tid & 15;                   // 16 u32 per thread

    // ---- prologue: h(t0) -> LDS (cross-launch visible at dispatch bound) ----
    {
        const unsigned int* hsrc = hx32 + (size_t)(t0 & 1) * BUFU32
                                 + grp * 8192 + hrow * 256 + hseg * 16;
        u32x4 hv0, hv1, hv2, hv3;
        ld4_coh(hsrc + 0,  hv0);
        ld4_coh(hsrc + 4,  hv1);
        ld4_coh(hsrc + 8,  hv2);
        ld4_coh(hsrc + 12, hv3);
        asm volatile("s_waitcnt vmcnt(0)" ::: "memory");
        unsigned int* d = &hl32[hrow * 260 + hseg * 16];
        *(u32x4*)(d + 0)  = hv0;
        *(u32x4*)(d + 4)  = hv1;
        *(u32x4*)(d + 8)  = hv2;
        *(u32x4*)(d + 12) = hv3;
    }
    // ---- prologue: xg prefetch for s=0 ----
    unsigned short pxr[4], pxz[4], pxn[4];
    if (w < 2) {
#pragma unroll
        for (int q = 0; q < 4; ++q) {
            const int row = w * 16 + (l >> 4) * 4 + q;
            const size_t rb = ((size_t)(b0 + row)) * G3;
            pxr[q] = xg_cur[rb + col];
            pxz[q] = xg_cur[rb + H + col];
            pxn[q] = xg_cur[rb + 2 * H + col];
        }
    }
    __syncthreads();                             // syncB: h(0) staged

    for (int s = 0; s < TCHUNK; ++s) {
        const int t = t0 + s;
        if (w < 2) {
            // ---- MFMA: 16 rows x 16 cols x 3 gates, K=512 ----
            f32x4 a0 = {}, a1 = {}, a2 = {};
#pragma unroll
            for (int kt = 0; kt < 16; ++kt) {
                const int ko = kt * 32 + (l >> 4) * 8;
                bf16x8 a = *(const bf16x8*)&h_lds[w * 16 + (l & 15)][ko];
                bf16x8 b0v = *(const bf16x8*)&wlds[0][l & 15][ko];
                bf16x8 b1v = *(const bf16x8*)&wlds[1][l & 15][ko];
                bf16x8 b2v = *(const bf16x8*)&wlds[2][l & 15][ko];
                a0 = __builtin_amdgcn_mfma_f32_16x16x32_bf16(a, b0v, a0, 0, 0, 0);
                a1 = __builtin_amdgcn_mfma_f32_16x16x32_bf16(a, b1v, a1, 0, 0, 0);
                a2 = __builtin_amdgcn_mfma_f32_16x16x32_bf16(a, b2v, a2, 0, 0, 0);
            }
            // ---- gates + state update ----
            unsigned int* hdst = hx32w + (size_t)((t + 1) & 1) * BUFU32 + grp * 8192;
            unsigned short hb[4];
            float ho4[4];
#pragma unroll
            for (int q = 0; q < 4; ++q) {
                const float pr = bf2f(pxr[q]) + a0[q];
                const float pz = bf2f(pxz[q]) + a1[q];
                const float r = pr / (1.f + __expf(-pr));    // silu
                const float z = pz / (1.f + __expf(-pz));
                const float n = tanhf(bf2f(pxn[q]) + r * (a2[q] + bnv));
                const float ho = (1.f - z) * n + z * hreg[q];
                hreg[q] = ho;
                ho4[q] = ho;
                hb[q] = f2bf(ho);
            }
            // ---- h stores FIRST (agent), per-wave drain, then flag ----
#pragma unroll
            for (int q = 0; q < 4; ++q) {
                unsigned int other = __shfl_xor((unsigned int)hb[q], 1);
                if ((l & 1) == 0) {
                    const int row = w * 16 + (l >> 4) * 4 + q;
                    unsigned int val = (unsigned int)hb[q] | (other << 16);
                    __hip_atomic_store(hdst + row * 256 + (col >> 1), val,
                                       __ATOMIC_RELAXED, __HIP_MEMORY_SCOPE_AGENT);
                }
            }
            asm volatile("s_waitcnt vmcnt(0)" ::: "memory");  // wave's h visible
            if (l == 0)
                __hip_atomic_store(flown, (unsigned int)(s + 1),
                                   __ATOMIC_RELAXED, __HIP_MEMORY_SCOPE_AGENT);
            // ---- ys / carry stores (drain under next phase) ----
            float* yst = ys + (size_t)t * BATCH * H;
#pragma unroll
            for (int q = 0; q < 4; ++q) {
                const int row = w * 16 + (l >> 4) * 4 + q;
                const size_t o = (size_t)(b0 + row) * H + col;
                yst[o] = ho4[q];
                if (t == T_STEPS - 1) carry[o] = ho4[q];
            }
        } else if (w == 7 && s + 1 < TCHUNK) {
            // ---- poller: wait for ALL 64 group flags >= s+1 (overlapped) ----
            const unsigned int tgt = (unsigned int)(s + 1);
            int guard = 0;
            for (;;) {
                unsigned int fv = __hip_atomic_load(flbase + l * 16,
                                                    __ATOMIC_RELAXED,
                                                    __HIP_MEMORY_SCOPE_AGENT);
                if (__all((int)(fv >= tgt))) break;
                if (++guard > 8192) break;       // fail loud, never hang
                __builtin_amdgcn_s_sleep(1);
            }
        }
        __syncthreads();                         // syncC: flags>=s+1 observed
        if (s + 1 < TCHUNK) {
            // ---- h(s+1) load -> LDS (coherent) ----
            const unsigned int* hsrc = hx32 + (size_t)((t + 1) & 1) * BUFU32
                                     + grp * 8192 + hrow * 256 + hseg * 16;
            u32x4 hv0, hv1, hv2, hv3;
            ld4_coh(hsrc + 0,  hv0);
            ld4_coh(hsrc + 4,  hv1);
            ld4_coh(hsrc + 8,  hv2);
            ld4_coh(hsrc + 12, hv3);
            // xg prefetch for s+1 (plain; completes under MFMA)
            if (w < 2) {
#pragma unroll
                for (int q = 0; q < 4; ++q) {
                    const int row = w * 16 + (l >> 4) * 4 + q;
                    const size_t rb = ((size_t)(s + 1) * BATCH + b0 + row) * G3;
                    pxr[q] = xg_cur[rb + col];
                    pxz[q] = xg_cur[rb + H + col];
                    pxn[q] = xg_cur[rb + 2 * H + col];
                }
            }
            asm volatile("s_waitcnt vmcnt(0)" ::: "memory");
            unsigned int* d = &hl32[hrow * 260 + hseg * 16];
            *(u32x4*)(d + 0)  = hv0;
            *(u32x4*)(d + 4)  = hv1;
            *(u32x4*)(d + 8)  = hv2;
            *(u32x4*)(d + 12) = hv3;
            __syncthreads();                     // syncB: h(s+1) staged
        }
    }
}

// ---------------------------------------------------------------------------
extern "C" void kernel_launch(void* const* d_in, const int* in_sizes, int n_in,
                              void* d_out, int out_size, void* d_ws, size_t ws_size,
                              hipStream_t stream) {
    const float* h0   = (const float*)d_in[0];
    const float* x    = (const float*)d_in[1];
    const float* Wi   = (const float*)d_in[2];
    const float* bi   = (const float*)d_in[3];
    const float* Whrz = (const float*)d_in[4];
    const float* Whn  = (const float*)d_in[5];
    const float* bhn  = (const float*)d_in[6];

    float* carry = (float*)d_out;
    float* ys    = (float*)d_out + (size_t)BATCH * H;

    // ws: wiT | whT | xgb0 | xgb1 | hx (bf16 [2][B][H]) | flags (16 x FPAGE)
    unsigned short* wiT  = (unsigned short*)d_ws;
    unsigned short* whT  = wiT + (size_t)G3 * KPAD;
    unsigned short* xgb0 = whT + (size_t)G3 * H;
    unsigned short* xgb1 = xgb0 + (size_t)MCHUNK * G3;
    unsigned short* hx   = xgb1 + (size_t)MCHUNK * G3;
    unsigned int*   flags = (unsigned int*)(hx + (size_t)2 * BATCH * H);

    transpose_wi<<<dim3(KPAD / 32, G3 / 32), dim3(32, 8), 0, stream>>>(Wi, wiT);
    transpose_wh<<<dim3(H / 32, G3 / 32), dim3(32, 8), 0, stream>>>(Whrz, Whn, whT);
    init_ws<<<dim3(256), 256, 0, stream>>>(h0, hx, flags);

    // chunk 0 xg (exposed once)
    gemm_xg<<<dim3(G3 / 128, MCHUNK / 128), 256, 0, stream>>>(x, wiT, bi, xgb0);

    for (int c = 0; c < NCHUNK; ++c) {
        const int t0 = c * TCHUNK;
        unsigned short* xg_cur  = (c & 1) ? xgb1 : xgb0;
        unsigned short* xg_next = (c & 1) ? xgb0 : xgb1;
        const float* hinit = (c == 0) ? h0 : ys + (size_t)(t0 - 1) * BATCH * H;
        const float* x_next = (c + 1 < NCHUNK) ? x + (size_t)(c + 1) * MCHUNK * F_IN
                                               : x;
        fused_chunk<<<dim3(RBLK + NWORK), 512, 0, stream>>>(
            x_next, wiT, bi, xg_next, xg_cur, whT, bhn, hinit,
            hx, ys, carry, flags + (size_t)c * FPAGE, t0,
            (c + 1 < NCHUNK) ? 1 : 0);
    }
}

// Round 11
// 2000.407 us; speedup vs baseline: 1.2101x; 1.2101x over previous
//
#include <hip/hip_runtime.h>
#include <cstddef>
#include <cstdint>

// ---------------------------------------------------------------------------
// GRU sequence model (flax GRUCell, gate_fn=silu, activation=tanh)
// T=512, B=128, F_IN=1030, H=512
// Round-11 = round-9 (proven 2043us) + epilogue reorder:
//   h stores -> __syncthreads (agent-ack only) -> flag -> ys/carry stores
//   (nontemporal, drain in background under next poll/load window).
//   r10 lesson: poll only in the wait window; continuous polling taxes the
//   producer-side coherence fabric (r10 regressed 2043->2420).
// Design recap (r9):
//   - 128 recurrence blocks: 4 groups x 32 batch rows; 32 col-blocks x 16
//     cols. Wh slice (48KB) LDS-resident. 83200B LDS => 1 block/CU; grid 248.
//   - per-step sync (agent-scope only): per-block flag word (atomic_store);
//     poll = wave0 lanes 0..31 load 32 flags + __all; h data: sc0sc1 dwordx4
//     loads + relaxed-agent u32 stores. Guard 4096 -> fails loud, never hangs.
//   - blocks 128..247: GEMM workers computing next chunk's xg (double buffer).
// Output: [carry (B*H) | ys (T*B*H)] fp32
// ---------------------------------------------------------------------------

#define T_STEPS 512
#define BATCH   128
#define F_IN    1030
#define KPAD    1056          // 33 * 32
#define H       512
#define G3      1536          // 3*H
#define TCHUNK  32
#define NCHUNK  (T_STEPS / TCHUNK)        // 16
#define MCHUNK  (TCHUNK * BATCH)          // 4096 rows per chunk
#define NTILE_M (MCHUNK / 128)            // 32
#define NTILE_N (G3 / 256)                // 6
#define NTILE   (NTILE_M * NTILE_N)       // 192
#define RBLK    128                       // recurrence blocks
#define NWORK   120                       // worker blocks
#define FPAGE   4096                      // u32 per launch flag page
#define BUFU32  32768                     // u32 per h buffer (B*H/2)

using f32x4  = __attribute__((ext_vector_type(4)))  float;
using bf16x8 = __attribute__((ext_vector_type(8)))  short;
using u16x8  = __attribute__((ext_vector_type(8)))  unsigned short;
using u32x4  = __attribute__((ext_vector_type(4)))  unsigned int;

__device__ __forceinline__ unsigned short f2bf(float f) {
    unsigned int u = __builtin_bit_cast(unsigned int, f);
    u = (u + 0x7FFFu + ((u >> 16) & 1u)) >> 16;   // RNE
    return (unsigned short)u;
}
__device__ __forceinline__ float bf2f(unsigned short s) {
    unsigned int u = ((unsigned int)s) << 16;
    return __builtin_bit_cast(float, u);
}
__device__ __forceinline__ unsigned int cvt2bf(float lo, float hi) {
    unsigned int r;
    asm("v_cvt_pk_bf16_f32 %0, %1, %2" : "=v"(r) : "v"(lo), "v"(hi));
    return r;
}
// coherent 16B load (bypass L1+L2 staleness); caller waits vmcnt
__device__ __forceinline__ void ld4_coh(const unsigned int* p, u32x4& d) {
    asm volatile("global_load_dwordx4 %0, %1, off sc0 sc1"
                 : "=&v"(d) : "v"(p) : "memory");
}

// ---------------------------------------------------------------------------
// Wi [F_IN][G3] fp32 -> wiT [G3][KPAD] bf16 (transposed, K zero-padded)
// ---------------------------------------------------------------------------
__global__ __launch_bounds__(256) void transpose_wi(const float* __restrict__ Wi,
                                                    unsigned short* __restrict__ wiT) {
    __shared__ float t_lds[32][33];
    const int kx = blockIdx.x, gy = blockIdx.y;
    const int tx = threadIdx.x, ty = threadIdx.y;
#pragma unroll
    for (int r = 0; r < 4; ++r) {
        int k = kx * 32 + ty + r * 8;
        int g = gy * 32 + tx;
        t_lds[ty + r * 8][tx] = (k < F_IN) ? Wi[(size_t)k * G3 + g] : 0.f;
    }
    __syncthreads();
#pragma unroll
    for (int r = 0; r < 4; ++r) {
        int g = gy * 32 + ty + r * 8;
        int k = kx * 32 + tx;
        wiT[(size_t)g * KPAD + k] = f2bf(t_lds[tx][ty + r * 8]);
    }
}

// ---------------------------------------------------------------------------
// Wh_rz [H][2H], Wh_n [H][H] fp32 -> whT [G3][H] bf16 column-major
// ---------------------------------------------------------------------------
__global__ __launch_bounds__(256) void transpose_wh(const float* __restrict__ Whrz,
                                                    const float* __restrict__ Whn,
                                                    unsigned short* __restrict__ whT) {
    __shared__ float t_lds[32][33];
    const int kx = blockIdx.x, cy = blockIdx.y;
    const int tx = threadIdx.x, ty = threadIdx.y;
#pragma unroll
    for (int r = 0; r < 4; ++r) {
        int k = kx * 32 + ty + r * 8;
        int c = cy * 32 + tx;
        float v = (c < 1024) ? Whrz[(size_t)k * 1024 + c]
                             : Whn[(size_t)k * H + (c - 1024)];
        t_lds[ty + r * 8][tx] = v;
    }
    __syncthreads();
#pragma unroll
    for (int r = 0; r < 4; ++r) {
        int c = cy * 32 + ty + r * 8;
        int k = kx * 32 + tx;
        whT[(size_t)c * H + k] = f2bf(t_lds[tx][ty + r * 8]);
    }
}

// ---------------------------------------------------------------------------
// init: hx[0] = bf16(h0); zero all launch flag pages (16 x 4096 u32)
// ---------------------------------------------------------------------------
__global__ __launch_bounds__(256) void init_ws(const float* __restrict__ h0,
                                               unsigned short* __restrict__ hx,
                                               unsigned int* __restrict__ flags) {
    int i = blockIdx.x * 256 + threadIdx.x;
    flags[i] = 0u;                       // 65536 u32 = 16 pages x 4096
    if (i < BATCH * H) hx[i] = f2bf(h0[i]);
}

// ---------------------------------------------------------------------------
// Standalone xg GEMM for chunk 0. 128x128 tile, BK=32, 256 thr.
// grid (G3/128=12, MCHUNK/128=32)
// ---------------------------------------------------------------------------
__global__ __launch_bounds__(256) void gemm_xg(const float* __restrict__ x,
                                               const unsigned short* __restrict__ wiT,
                                               const float* __restrict__ bi,
                                               unsigned short* __restrict__ xg) {
    __shared__ unsigned short a_lds[128][40];
    __shared__ unsigned short b_lds[128][40];
    const int tid = threadIdx.x;
    const int n0 = blockIdx.x * 128;
    const int m0 = blockIdx.y * 128;
    const int l = tid & 63, w = tid >> 6;
    const int wr = w >> 1, wc = w & 1;
    const int sr = tid >> 1;
    const int sk = (tid & 1) * 16;

    f32x4 acc[4][4] = {};

    for (int kt = 0; kt < 33; ++kt) {
        if (kt) __syncthreads();
        {
            const int kb = kt * 32 + sk;
            const float* srcp = x + (size_t)(m0 + sr) * F_IN + kb;
            float2 f2v[8];
#pragma unroll
            for (int i = 0; i < 8; ++i) {
                int k = kb + 2 * i;
                if (k < F_IN) f2v[i] = *(const float2*)(srcp + 2 * i);
                else          f2v[i] = make_float2(0.f, 0.f);
            }
            uint4 p0, p1;
            p0.x = cvt2bf(f2v[0].x, f2v[0].y); p0.y = cvt2bf(f2v[1].x, f2v[1].y);
            p0.z = cvt2bf(f2v[2].x, f2v[2].y); p0.w = cvt2bf(f2v[3].x, f2v[3].y);
            p1.x = cvt2bf(f2v[4].x, f2v[4].y); p1.y = cvt2bf(f2v[5].x, f2v[5].y);
            p1.z = cvt2bf(f2v[6].x, f2v[6].y); p1.w = cvt2bf(f2v[7].x, f2v[7].y);
            *(uint4*)&a_lds[sr][sk]     = p0;
            *(uint4*)&a_lds[sr][sk + 8] = p1;
            const unsigned short* bsrc = wiT + (size_t)(n0 + sr) * KPAD + kb;
            *(uint4*)&b_lds[sr][sk]     = *(const uint4*)bsrc;
            *(uint4*)&b_lds[sr][sk + 8] = *(const uint4*)(bsrc + 8);
        }
        __syncthreads();
        const int ka = (l >> 4) * 8;
        bf16x8 af[4], bfr[4];
#pragma unroll
        for (int mi = 0; mi < 4; ++mi)
            af[mi] = *(const bf16x8*)&a_lds[wr * 64 + mi * 16 + (l & 15)][ka];
#pragma unroll
        for (int nj = 0; nj < 4; ++nj)
            bfr[nj] = *(const bf16x8*)&b_lds[wc * 64 + nj * 16 + (l & 15)][ka];
#pragma unroll
        for (int mi = 0; mi < 4; ++mi)
#pragma unroll
            for (int nj = 0; nj < 4; ++nj)
                acc[mi][nj] = __builtin_amdgcn_mfma_f32_16x16x32_bf16(
                    af[mi], bfr[nj], acc[mi][nj], 0, 0, 0);
    }

#pragma unroll
    for (int nj = 0; nj < 4; ++nj) {
        const int col = n0 + wc * 64 + nj * 16 + (l & 15);
        const float bv = bi[col];
#pragma unroll
        for (int mi = 0; mi < 4; ++mi) {
#pragma unroll
            for (int q = 0; q < 4; ++q) {
                const int row = m0 + wr * 64 + mi * 16 + (l >> 4) * 4 + q;
                xg[(size_t)row * G3 + col] = f2bf(acc[mi][nj][q] + bv);
            }
        }
    }
}

// ---------------------------------------------------------------------------
// Fused chunk kernel: 248 blocks x 512 thr, 83200B LDS => 1 block/CU.
// blockIdx < 128: recurrence. blockIdx >= 128: GEMM workers.
// ---------------------------------------------------------------------------
__global__ __launch_bounds__(512) void fused_chunk(
    const float* __restrict__ x_next,          // x rows for chunk c+1
    const unsigned short* __restrict__ wiT,
    const float* __restrict__ bi,
    unsigned short* __restrict__ xg_next,      // xg buffer for chunk c+1
    const unsigned short* __restrict__ xg_cur, // xg buffer for chunk c
    const unsigned short* __restrict__ whT,    // [G3][H] bf16
    const float* __restrict__ bhn,
    const float* __restrict__ hinit,           // fp32 h at t0 (h0 or ys[t0-1])
    unsigned short* __restrict__ hx,           // [2][B][H] bf16
    float* __restrict__ ys,                    // [T][B][H] fp32
    float* __restrict__ carry,                 // [B][H] fp32
    unsigned int* __restrict__ fpage,          // this launch's flag page
    int t0, int do_gemm)
{
    __shared__ __align__(16) unsigned char smem[83200];
    const int tid = threadIdx.x;
    const int bid = blockIdx.x;
    const int l = tid & 63, w = tid >> 6;

    if (bid >= RBLK) {
        // ================= GEMM worker path =================
        if (!do_gemm) return;
        unsigned short (*a_lds)[40] = (unsigned short(*)[40])smem;            // 128x40
        unsigned short (*b_lds)[40] = (unsigned short(*)[40])(smem + 10240);  // 256x40
        const int wr = w & 1, wc = w >> 1;       // 2(m) x 4(n) waves, 64x64 each
        const int sa_r = tid >> 2;               // 0..127
        const int sa_k = (tid & 3) * 8;
        const int sb_r = tid >> 1;               // 0..255
        const int sb_k = (tid & 1) * 16;

        for (int tile = bid - RBLK; tile < NTILE; tile += NWORK) {
            const int m0 = (tile & (NTILE_M - 1)) * 128;
            const int n0 = (tile / NTILE_M) * 256;
            f32x4 acc[4][4] = {};
            for (int kt = 0; kt < 33; ++kt) {
                __syncthreads();
                {
                    const int kb = kt * 32 + sa_k;
                    const float* srcp = x_next + (size_t)(m0 + sa_r) * F_IN + kb;
                    float2 f2v[4];
#pragma unroll
                    for (int i = 0; i < 4; ++i) {
                        int k = kb + 2 * i;
                        if (k < F_IN) f2v[i] = *(const float2*)(srcp + 2 * i);
                        else          f2v[i] = make_float2(0.f, 0.f);
                    }
                    uint4 p;
                    p.x = cvt2bf(f2v[0].x, f2v[0].y); p.y = cvt2bf(f2v[1].x, f2v[1].y);
                    p.z = cvt2bf(f2v[2].x, f2v[2].y); p.w = cvt2bf(f2v[3].x, f2v[3].y);
                    *(uint4*)&a_lds[sa_r][sa_k] = p;
                    const int kbB = kt * 32 + sb_k;
                    const unsigned short* bsrc = wiT + (size_t)(n0 + sb_r) * KPAD + kbB;
                    *(uint4*)&b_lds[sb_r][sb_k]     = *(const uint4*)bsrc;
                    *(uint4*)&b_lds[sb_r][sb_k + 8] = *(const uint4*)(bsrc + 8);
                }
                __syncthreads();
                const int ka = (l >> 4) * 8;
                bf16x8 af[4], bfr[4];
#pragma unroll
                for (int mi = 0; mi < 4; ++mi)
                    af[mi] = *(const bf16x8*)&a_lds[wr * 64 + mi * 16 + (l & 15)][ka];
#pragma unroll
                for (int nj = 0; nj < 4; ++nj)
                    bfr[nj] = *(const bf16x8*)&b_lds[wc * 64 + nj * 16 + (l & 15)][ka];
#pragma unroll
                for (int mi = 0; mi < 4; ++mi)
#pragma unroll
                    for (int nj = 0; nj < 4; ++nj)
                        acc[mi][nj] = __builtin_amdgcn_mfma_f32_16x16x32_bf16(
                            af[mi], bfr[nj], acc[mi][nj], 0, 0, 0);
            }
#pragma unroll
            for (int nj = 0; nj < 4; ++nj) {
                const int col = n0 + wc * 64 + nj * 16 + (l & 15);
                const float bv = bi[col];
#pragma unroll
                for (int mi = 0; mi < 4; ++mi) {
#pragma unroll
                    for (int q = 0; q < 4; ++q) {
                        const int row = m0 + wr * 64 + mi * 16 + (l >> 4) * 4 + q;
                        xg_next[(size_t)row * G3 + col] = f2bf(acc[mi][nj][q] + bv);
                    }
                }
            }
            __syncthreads();
        }
        return;
    }

    // ================= Recurrence path (bid 0..127) =================
    unsigned short (*wlds)[16][520] = (unsigned short(*)[16][520])smem;       // [3][16][520] 49920B
    unsigned short (*h_lds)[520]    = (unsigned short(*)[520])(smem + 49920); // [32][520]    33280B
    unsigned int* hl32 = (unsigned int*)(smem + 49920);                       // pitch 260 u32

    const int grp = bid >> 5;                    // 0..3 -> 32 batch rows
    const int rnk = bid & 31;                    // 0..31 -> 16 cols
    const int b0 = grp * 32;
    const int j0 = rnk * 16;
    unsigned int* flbase = fpage + grp * 1024;   // 32 flags, 128B apart
    unsigned int* flown  = flbase + rnk * 32;
    const unsigned int* hx32 = (const unsigned int*)hx;
    unsigned int* hx32w = (unsigned int*)hx;

    // ---- prologue: Wh slice -> LDS (once per launch) ----
#pragma unroll
    for (int it = 0; it < 6; ++it) {
        int L = tid + it * 512;                  // 0..3071 vec8 loads
        int gate = L >> 10;                      // 1024 per gate
        int rem = L & 1023;
        int jj = rem >> 6;                       // 0..15
        int k8 = (rem & 63) * 8;                 // 0..504
        *(u16x8*)&wlds[gate][jj][k8] =
            *(const u16x8*)(whT + ((size_t)(gate * H + j0 + jj)) * H + k8);
    }

    const int col = j0 + (l & 15);
    float hreg[4];
    if (w < 2) {
#pragma unroll
        for (int q = 0; q < 4; ++q) {
            const int row = w * 16 + (l >> 4) * 4 + q;
            hreg[q] = hinit[(size_t)(b0 + row) * H + col];
        }
    }
    const float bnv = bhn[col];
    const int hrow = tid >> 4;                   // 0..31 (h staging row)
    const int hseg = tid & 15;                   // 16 u32 per thread

    for (int s = 0; s < TCHUNK; ++s) {
        const int t = t0 + s;
        // ---- xg prefetch (plain; completes under poll/load) ----
        unsigned short pxr[4], pxz[4], pxn[4];
        if (w < 2) {
#pragma unroll
            for (int q = 0; q < 4; ++q) {
                const int row = w * 16 + (l >> 4) * 4 + q;
                const size_t rb = ((size_t)s * BATCH + b0 + row) * G3;
                pxr[q] = xg_cur[rb + col];
                pxz[q] = xg_cur[rb + H + col];
                pxn[q] = xg_cur[rb + 2 * H + col];
            }
        }
        // ---- wait for all 32 producers of h_t (windowed parallel poll) ----
        if (s > 0) {
            if (w == 0) {
                int guard = 0;
                for (;;) {
                    unsigned int fv = 0xFFFFFFFFu;
                    if (l < 32)
                        fv = __hip_atomic_load(flbase + l * 32, __ATOMIC_RELAXED,
                                               __HIP_MEMORY_SCOPE_AGENT);
                    if (__all((int)(fv >= (unsigned int)s))) break;
                    if (++guard > 4096) break;   // fail loud, never hang
                    __builtin_amdgcn_s_sleep(1);
                }
            }
            __syncthreads();
        }
        // ---- h_t load: coherent 64B/thread from hx[t&1] ----
        const unsigned int* hsrc = hx32 + (size_t)(t & 1) * BUFU32
                                 + grp * 8192 + hrow * 256 + hseg * 16;
        u32x4 hv0, hv1, hv2, hv3;
        ld4_coh(hsrc + 0,  hv0);
        ld4_coh(hsrc + 4,  hv1);
        ld4_coh(hsrc + 8,  hv2);
        ld4_coh(hsrc + 12, hv3);
        asm volatile("s_waitcnt vmcnt(0)" ::: "memory");
        {
            unsigned int* d = &hl32[hrow * 260 + hseg * 16];
            *(u32x4*)(d + 0)  = hv0;
            *(u32x4*)(d + 4)  = hv1;
            *(u32x4*)(d + 8)  = hv2;
            *(u32x4*)(d + 12) = hv3;
        }
        __syncthreads();
        // ---- compute waves: MFMA 3 gates, wave w = M-tile ----
        float ho4[4];
        if (w < 2) {
            f32x4 a0 = {}, a1 = {}, a2 = {};
#pragma unroll
            for (int kt = 0; kt < 16; ++kt) {
                const int ko = kt * 32 + (l >> 4) * 8;
                bf16x8 a = *(const bf16x8*)&h_lds[w * 16 + (l & 15)][ko];
                bf16x8 b0v = *(const bf16x8*)&wlds[0][l & 15][ko];
                bf16x8 b1v = *(const bf16x8*)&wlds[1][l & 15][ko];
                bf16x8 b2v = *(const bf16x8*)&wlds[2][l & 15][ko];
                a0 = __builtin_amdgcn_mfma_f32_16x16x32_bf16(a, b0v, a0, 0, 0, 0);
                a1 = __builtin_amdgcn_mfma_f32_16x16x32_bf16(a, b1v, a1, 0, 0, 0);
                a2 = __builtin_amdgcn_mfma_f32_16x16x32_bf16(a, b2v, a2, 0, 0, 0);
            }
            // ---- gates + state update; h stores ONLY (agent) ----
            unsigned int* hdst = hx32w + (size_t)((t + 1) & 1) * BUFU32 + grp * 8192;
            unsigned short hb[4];
#pragma unroll
            for (int q = 0; q < 4; ++q) {
                const float pr = bf2f(pxr[q]) + a0[q];
                const float pz = bf2f(pxz[q]) + a1[q];
                const float r = pr / (1.f + __expf(-pr));    // silu
                const float z = pz / (1.f + __expf(-pz));
                const float n = tanhf(bf2f(pxn[q]) + r * (a2[q] + bnv));
                const float ho = (1.f - z) * n + z * hreg[q];
                hreg[q] = ho;
                ho4[q] = ho;
                hb[q] = f2bf(ho);
            }
#pragma unroll
            for (int q = 0; q < 4; ++q) {
                unsigned int other = __shfl_xor((unsigned int)hb[q], 1);
                if ((l & 1) == 0) {
                    const int row = w * 16 + (l >> 4) * 4 + q;
                    unsigned int val = (unsigned int)hb[q] | (other << 16);
                    __hip_atomic_store(hdst + row * 256 + (col >> 1), val,
                                       __ATOMIC_RELAXED, __HIP_MEMORY_SCOPE_AGENT);
                }
            }
        }
        __syncthreads();          // drains h stores only (agent-ack, fast)
        if (tid == 0)
            __hip_atomic_store(flown, (unsigned int)(s + 1),
                               __ATOMIC_RELAXED, __HIP_MEMORY_SCOPE_AGENT);
        // ---- ys / carry stores AFTER flag (nontemporal, drain in bg) ----
        if (w < 2) {
            float* yst = ys + (size_t)t * BATCH * H;
#pragma unroll
            for (int q = 0; q < 4; ++q) {
                const int row = w * 16 + (l >> 4) * 4 + q;
                const size_t o = (size_t)(b0 + row) * H + col;
                __builtin_nontemporal_store(ho4[q], &yst[o]);
                if (t == T_STEPS - 1) carry[o] = ho4[q];
            }
        }
    }
}

// ---------------------------------------------------------------------------
extern "C" void kernel_launch(void* const* d_in, const int* in_sizes, int n_in,
                              void* d_out, int out_size, void* d_ws, size_t ws_size,
                              hipStream_t stream) {
    const float* h0   = (const float*)d_in[0];
    const float* x    = (const float*)d_in[1];
    const float* Wi   = (const float*)d_in[2];
    const float* bi   = (const float*)d_in[3];
    const float* Whrz = (const float*)d_in[4];
    const float* Whn  = (const float*)d_in[5];
    const float* bhn  = (const float*)d_in[6];

    float* carry = (float*)d_out;
    float* ys    = (float*)d_out + (size_t)BATCH * H;

    // ws: wiT | whT | xgb0 | xgb1 | hx (bf16 [2][B][H]) | flags (16 x FPAGE)
    unsigned short* wiT  = (unsigned short*)d_ws;
    unsigned short* whT  = wiT + (size_t)G3 * KPAD;
    unsigned short* xgb0 = whT + (size_t)G3 * H;
    unsigned short* xgb1 = xgb0 + (size_t)MCHUNK * G3;
    unsigned short* hx   = xgb1 + (size_t)MCHUNK * G3;
    unsigned int*   flags = (unsigned int*)(hx + (size_t)2 * BATCH * H);

    transpose_wi<<<dim3(KPAD / 32, G3 / 32), dim3(32, 8), 0, stream>>>(Wi, wiT);
    transpose_wh<<<dim3(H / 32, G3 / 32), dim3(32, 8), 0, stream>>>(Whrz, Whn, whT);
    init_ws<<<dim3(256), 256, 0, stream>>>(h0, hx, flags);

    // chunk 0 xg (exposed once)
    gemm_xg<<<dim3(G3 / 128, MCHUNK / 128), 256, 0, stream>>>(x, wiT, bi, xgb0);

    for (int c = 0; c < NCHUNK; ++c) {
        const int t0 = c * TCHUNK;
        unsigned short* xg_cur  = (c & 1) ? xgb1 : xgb0;
        unsigned short* xg_next = (c & 1) ? xgb0 : xgb1;
        const float* hinit = (c == 0) ? h0 : ys + (size_t)(t0 - 1) * BATCH * H;
        const float* x_next = (c + 1 < NCHUNK) ? x + (size_t)(c + 1) * MCHUNK * F_IN
                                               : x;
        fused_chunk<<<dim3(RBLK + NWORK), 512, 0, stream>>>(
            x_next, wiT, bi, xg_next, xg_cur, whT, bhn, hinit,
            hx, ys, carry, flags + (size_t)c * FPAGE, t0,
            (c + 1 < NCHUNK) ? 1 : 0);
    }
}